// Round 14
// baseline (576.951 us; speedup 1.0000x reference)
//
#include <hip/hip_runtime.h>
#include <hip/hip_fp16.h>
#include <stdint.h>

typedef _Float16 f16;
typedef __attribute__((ext_vector_type(4))) _Float16 f16x4;
typedef __attribute__((ext_vector_type(8))) _Float16 f16x8;
typedef __attribute__((ext_vector_type(4))) float f32x4;

#define DEVI static __device__ __forceinline__

// ---- constants for this problem ----
#define C_DIM 512
#define M1    113288   // 8*289*49 window-token rows
#define M2    102152   // 8*12769 pixel rows
#define NWIN  289
#define NTOK  49
#define NHW   18496    // 8*289*8 head-windows
#define QKV_STRIDE 3136  // 49*64 per head-window, q/k/v all

DEVI void load_lds16(const f16* g, f16* l) {
  __builtin_amdgcn_global_load_lds((const __attribute__((address_space(1))) void*)g,
                                   (__attribute__((address_space(3))) void*)l,
                                   16, 0, 0);
}

DEVI f32x4 mfma_16x16x32(f16x8 a, f16x8 b, f32x4 c) {
  return __builtin_amdgcn_mfma_f32_16x16x32_f16(a, b, c, 0, 0, 0);
}

// ---------------- x -> f16 (and zero page init) ----------------
__global__ void cvt_x_kernel(const float* __restrict__ x, f16* __restrict__ xh,
                             f16* __restrict__ zp) {
  if (blockIdx.x == 0 && threadIdx.x < 64) {
    ((int4*)zp)[threadIdx.x] = make_int4(0, 0, 0, 0);  // 1024 B zeros
  }
  const int n8 = 6537728;  // 52,301,824 / 8
  int i = blockIdx.x * blockDim.x + threadIdx.x;
  for (; i < n8; i += gridDim.x * blockDim.x) {
    const float4* p = (const float4*)(x) + (size_t)i * 2;
    const float4 a = p[0], b = p[1];
    f16x8 o;
    o[0] = (f16)a.x; o[1] = (f16)a.y; o[2] = (f16)a.z; o[3] = (f16)a.w;
    o[4] = (f16)b.x; o[5] = (f16)b.y; o[6] = (f16)b.z; o[7] = (f16)b.w;
    *(f16x8*)(xh + (size_t)i * 8) = o;
  }
}

// ---------------- W [K][N] -> Wt f16 [N][K] ----------------
__global__ void cvt_wT_kernel(const float* __restrict__ w, f16* __restrict__ wt,
                              int K, int N) {
  const int i = blockIdx.x * blockDim.x + threadIdx.x;
  if (i < K * N) {
    const int n = i / K;
    const int k = i - n * K;
    wt[i] = (f16)w[(size_t)k * N + n];
  }
}

// ================= GEMM: C[M][N] = gather(A)[M][512] @ Bt[N][512]^T =============
// 128x128 block tile, 4 waves (64x64 per wave), BK=64, SINGLE 32 KB LDS buffer,
// 2 barriers per K-tile. LDS [128 rows][8 chunks of 16B], phys chunk =
// logical ^ (row&7) via inverse-swizzled GLOBAL source + linear gload dest.
// MODE 0 epilogue: LDS-transpose -> coalesced f16x8 stores; q/k/v [hw][49][64].
// MODE 1 epilogue: two-half LDS-transpose (fp32 [64][128] in S) -> coalesced
//                  float4 stores; bias fused at LDS write.
template<int MODE>
__global__ __launch_bounds__(256, 2)
void gemm_kernel(const f16* __restrict__ A, const f16* __restrict__ Bt,
                 f16* __restrict__ qo, f16* __restrict__ ko, f16* __restrict__ vo,
                 float* __restrict__ out, const float* __restrict__ bias,
                 const f16* __restrict__ zp)
{
  __shared__ __align__(16) f16 S[16384];  // 32 KB: As | Bs during K-loop; Cs in epilogue
  f16* As = S;
  f16* Bs = S + 8192;

  const int tid  = threadIdx.x;
  const int wave = tid >> 6;
  const int lane = tid & 63;
  const int l16  = lane & 15;
  const int g    = lane >> 4;

  constexpr int NTN = (MODE == 0) ? 12 : 4;
  // bijective XCD swizzle, tn-fastest (all N-passes of an A-tile on one XCD)
  const int nwg = gridDim.x;
  const int qq = nwg >> 3, rr = nwg & 7;
  const int xcd = blockIdx.x & 7, ib = blockIdx.x >> 3;
  const int wg = (xcd < rr ? xcd * (qq + 1) : rr * (qq + 1) + (xcd - rr) * qq) + ib;
  const int tn = wg % NTN;
  const int tm = wg / NTN;

  // ---- staging source pointers: 4 row-groups of 32, one 16B chunk per thread ----
  const int srow  = tid >> 3;   // 0..31
  const int chunk = tid & 7;    // phys chunk slot (linear LDS dest)
  const int lc    = chunk ^ (srow & 7);  // logical k-chunk fetched into this slot
  const f16* asrc[4];
  const f16* bsrc[4];
  #pragma unroll
  for (int c = 0; c < 4; ++c) {
    const int m = tm * 128 + c * 32 + srow;
    long src = 0; bool valid;
    if (MODE == 0) {
      const int b   = m / 14161;               // 289*49
      const int rem = m - b * 14161;
      const int wi  = rem / 49;
      const int t   = rem - wi * 49;
      const int wh = wi / 17, ww = wi - (wi / 17) * 17;
      const int th = t / 7,   tw = t - (t / 7) * 7;
      const int h = wh * 7 + th, w = ww * 7 + tw;
      valid = (m < M1) && (h < 113) && (w < 113);
      src = (long)b * 12769 + h * 113 + w;
    } else {
      const int b = m / 12769;
      const int p = m - b * 12769;
      const int h = p / 113, w = p - (p / 113) * 113;
      valid = (m < M2);
      src = (long)((b * NWIN + (h / 7) * 17 + (w / 7)) * NTOK + (h % 7) * 7 + (w % 7));
    }
    asrc[c] = valid ? (A + src * C_DIM + lc * 8) : zp;
    bsrc[c] = Bt + (long)(tn * 128 + c * 32 + srow) * C_DIM + lc * 8;
  }

  // ---- ds_read byte offsets (kh=0; kh=1 => ^64) ----
  int aoff[4], boff[4];
  #pragma unroll
  for (int i = 0; i < 4; ++i) {
    const int ra = (wave >> 1) * 64 + 16 * i + l16;
    aoff[i] = ra * 128 + ((g ^ (l16 & 7)) << 4);
    const int rb = (wave & 1) * 64 + 16 * i + l16;
    boff[i] = rb * 128 + ((g ^ (l16 & 7)) << 4);
  }

  f32x4 acc[4][4];
  #pragma unroll
  for (int i = 0; i < 4; ++i)
    #pragma unroll
    for (int j = 0; j < 4; ++j)
      acc[i][j] = (f32x4){0.f, 0.f, 0.f, 0.f};

  for (int kk = 0; kk < 8; ++kk) {       // K = 512 = 8 * 64
    __syncthreads();                     // prior tile's reads done (WAR)
    #pragma unroll
    for (int c = 0; c < 4; ++c) {
      load_lds16(asrc[c], &As[c * 2048 + wave * 512]);
      asrc[c] += 64;
    }
    #pragma unroll
    for (int c = 0; c < 4; ++c) {
      load_lds16(bsrc[c], &Bs[c * 2048 + wave * 512]);
      bsrc[c] += 64;
    }
    __syncthreads();                     // staging complete (vmcnt drained)

    #pragma unroll
    for (int kh = 0; kh < 2; ++kh) {
      f16x8 af[4], bf[4];
      #pragma unroll
      for (int i = 0; i < 4; ++i) af[i] = *(const f16x8*)((const char*)As + (aoff[i] ^ (kh << 6)));
      #pragma unroll
      for (int j = 0; j < 4; ++j) bf[j] = *(const f16x8*)((const char*)Bs + (boff[j] ^ (kh << 6)));
      #pragma unroll
      for (int i = 0; i < 4; ++i)
        #pragma unroll
        for (int j = 0; j < 4; ++j)
          acc[i][j] = mfma_16x16x32(af[i], bf[j], acc[i][j]);
    }
  }

  // ---- epilogue ----
  if (MODE == 0) {
    // LDS-transpose: Cs[128 rows][128 cols] f16, byte-swizzle ^((row>>2&3)<<5)
    __syncthreads();                       // all waves done reading As/Bs
    char* Cs = (char*)S;
    const int rw0 = (wave >> 1) * 64 + g * 4;
    const int cl0 = (wave & 1) * 64 + l16;
    #pragma unroll
    for (int i = 0; i < 4; ++i) {
      #pragma unroll
      for (int rg = 0; rg < 4; ++rg) {
        const int row = rw0 + i * 16 + rg;
        const int xr  = ((row >> 2) & 3) << 5;
        #pragma unroll
        for (int j = 0; j < 4; ++j) {
          const int col = cl0 + j * 16;
          *(f16*)(Cs + row * 256 + ((col * 2) ^ xr)) = (f16)acc[i][j][rg];
        }
      }
    }
    __syncthreads();
    // read-out: thread -> (row, 64-col half); coalesced 16B global stores
    const int row  = tid >> 1;
    const int half = tid & 1;
    const int m = tm * 128 + row;
    if (m < M1) {
      const int bwi = m / 49;
      const int t   = m - bwi * 49;
      const int cwi = tn * 2 + half;            // 64-col strip index 0..23
      f16* outw = (cwi < 8) ? qo : (cwi < 16) ? ko : vo;
      const int head = cwi & 7;
      f16* dst = outw + (size_t)(bwi * 8 + head) * QKV_STRIDE + t * 64;
      const int xr = ((row >> 2) & 3) << 5;
      #pragma unroll
      for (int c = 0; c < 8; ++c) {
        f16x8 v = *(const f16x8*)(Cs + row * 256 + ((half * 128 + c * 16) ^ xr));
        *(f16x8*)(dst + c * 8) = v;
      }
    }
  } else {
    // two-half LDS transpose: Cs32 = fp32 [64][128] (32 KB), swizzle ^((row&7)<<4)
    char* Cs = (char*)S;
    const int colLoc = (wave & 1) * 64 + l16;   // 0..127 block-local col
    float bb[4];
    #pragma unroll
    for (int j = 0; j < 4; ++j) bb[j] = bias[tn * 128 + colLoc + j * 16];
    #pragma unroll
    for (int h = 0; h < 2; ++h) {
      __syncthreads();                    // As/Bs reads done (h=0) / readout done (h=1)
      if ((wave >> 1) == h) {
        #pragma unroll
        for (int i = 0; i < 4; ++i) {
          #pragma unroll
          for (int rg = 0; rg < 4; ++rg) {
            const int row = 16 * i + 4 * g + rg;    // 0..63 within half
            const int xr  = (row & 7) << 4;
            #pragma unroll
            for (int j = 0; j < 4; ++j)
              *(float*)(Cs + ((row * 512 + (colLoc + j * 16) * 4) ^ xr)) =
                  acc[i][j][rg] + bb[j];
          }
        }
      }
      __syncthreads();                    // half staged (lgkmcnt drained)
      const int row = tid >> 2, part = tid & 3;
      const int m = tm * 128 + h * 64 + row;
      if (m < M2) {
        float* dst = out + (size_t)m * C_DIM + tn * 128 + part * 32;
        const int xr = (row & 7) << 4;
        #pragma unroll
        for (int u = 0; u < 8; ++u) {
          float4 v = *(const float4*)(Cs + ((row * 512 + part * 128 + u * 16) ^ xr));
          *(float4*)(dst + u * 4) = v;
        }
      }
    }
  }
}

// ---------------- MFMA attention: one wave per (b, window, head) ----------------
// r8 split-buffer version + T5 setprio around MFMA clusters + LDS-transposed
// O-store (stage O into plds after PV -- per-wave DS in-order, no barrier needed;
// then lane=q reads its row and stores 128 B contiguous).
__global__ __launch_bounds__(256)
void attn_kernel(const f16* __restrict__ qg, const f16* __restrict__ kg,
                 const f16* __restrict__ vg, f16* __restrict__ og)
{
  __shared__ __align__(16) f16 plds[4][4096];  // per-wave [64q][64key], XOR-swizzled
  __shared__ __align__(16) f16 vlds[4][2048];  // per-wave [32d][64t] half, XOR-swizzled
  const int tid  = threadIdx.x;
  const int wv   = tid >> 6;
  const int lane = tid & 63;
  const int g    = lane >> 4;
  const int c    = lane & 15;
  const int hw   = blockIdx.x * 4 + wv;
  const int bwi  = hw >> 3;
  const int head = hw & 7;
  const int wi   = bwi % NWIN;
  const size_t bqk = (size_t)hw * QKV_STRIDE;
  const f16* vp = vg + (size_t)hw * QKV_STRIDE;

  // ---- V tile -> registers early (latency hides under QK^T); zero pad rows ----
  f16x8 vreg[8];
  #pragma unroll
  for (int d0 = 0; d0 < 8; ++d0)
    vreg[d0] = *(const f16x8*)(vp + lane * 64 + d0 * 8);
  if (lane >= 49) {
    #pragma unroll
    for (int d0 = 0; d0 < 8; ++d0) vreg[d0] = (f16x8){};
  }

  // pad-bit mask for tokens 0..48 of this window
  const int wh = wi / 17, ww = wi - (wi / 17) * 17;
  unsigned long long pm = 0;
  if (wh == 16) pm |= (((1ull << 49) - 1) & ~0x7Full);           // rows th>=1
  if (ww == 16) {
    unsigned long long cm = 0;
    #pragma unroll
    for (int r7 = 0; r7 < 7; ++r7) cm |= 0x7Eull << (7 * r7);    // cols tw>=1
    pm |= cm;
  }

  // ---- S^T = K * Q^T ----
  f32x4 acc[4][4];
  #pragma unroll
  for (int i = 0; i < 4; ++i)
    #pragma unroll
    for (int j = 0; j < 4; ++j) acc[i][j] = (f32x4){0.f, 0.f, 0.f, 0.f};

  const f16* kp = kg + bqk;
  const f16* qp = qg + bqk;
  __builtin_amdgcn_s_setprio(1);
  #pragma unroll
  for (int s = 0; s < 2; ++s) {
    f16x8 kf[4], qf[4];
    #pragma unroll
    for (int i = 0; i < 4; ++i) kf[i] = *(const f16x8*)(kp + (16 * i + c) * 64 + 32 * s + 8 * g);
    #pragma unroll
    for (int j = 0; j < 4; ++j) qf[j] = *(const f16x8*)(qp + (16 * j + c) * 64 + 32 * s + 8 * g);
    #pragma unroll
    for (int i = 0; i < 4; ++i)
      #pragma unroll
      for (int j = 0; j < 4; ++j)
        acc[i][j] = mfma_16x16x32(kf[i], qf[j], acc[i][j]);
  }
  __builtin_amdgcn_s_setprio(0);

  // ---- mask + exp + per-query denom (q = 16j + c; key = 16i + 4g + r) ----
  float invs[4];
  #pragma unroll
  for (int j = 0; j < 4; ++j) {
    const int q = 16 * j + c;
    const int padq = (int)((pm >> q) & 1);
    float sj = 0.f;
    #pragma unroll
    for (int i = 0; i < 4; ++i) {
      #pragma unroll
      for (int r = 0; r < 4; ++r) {
        const int key = 16 * i + 4 * g + r;
        const int padk = (int)((pm >> key) & 1);
        float sv = acc[i][j][r] * 0.125f + ((padk ^ padq) ? -1000.f : 0.f);
        float p = __expf(sv);
        if (i == 3) p = ((4 * g + r) == 0) ? p : 0.f;   // keys >= 49 forced 0
        acc[i][j][r] = p;
        sj += p;
      }
    }
    invs[j] = sj;
  }
  #pragma unroll
  for (int j = 0; j < 4; ++j) {
    float sj = invs[j];
    sj += __shfl_xor(sj, 16);
    sj += __shfl_xor(sj, 32);
    invs[j] = 1.0f / sj;
  }

  // ---- pack normalized P to f16, write LDS [q][key] (byte ^= (q&7)<<4) ----
  f16* pl = &plds[wv][0];
  const int swz = (c & 7) << 4;   // c&7 == q&7 for all j
  #pragma unroll
  for (int j = 0; j < 4; ++j) {
    const int q = 16 * j + c;
    const float inv = invs[j];
    #pragma unroll
    for (int i = 0; i < 4; ++i) {
      f16x4 pk;
      pk[0] = (f16)(acc[i][j][0] * inv);
      pk[1] = (f16)(acc[i][j][1] * inv);
      pk[2] = (f16)(acc[i][j][2] * inv);
      pk[3] = (f16)(acc[i][j][3] * inv);
      *(f16x4*)((char*)pl + q * 128 + ((32 * i + 8 * g) ^ swz)) = pk;
    }
  }

  // ---- O = P * V in two d-halves; V^T built in LDS from vreg ----
  f16* vl = &vlds[wv][0];
  f32x4 o[4][4];
  #pragma unroll
  for (int i = 0; i < 4; ++i)
    #pragma unroll
    for (int j = 0; j < 4; ++j) o[i][j] = (f32x4){0.f, 0.f, 0.f, 0.f};

  #pragma unroll
  for (int h = 0; h < 2; ++h) {
    #pragma unroll
    for (int q4 = 0; q4 < 4; ++q4) {
      const int d0 = 4 * h + q4;
      #pragma unroll
      for (int j = 0; j < 8; ++j) {
        const int dr = (8 * d0 + j) & 31;
        *(f16*)((char*)vl + dr * 128 + ((lane * 2) ^ (j << 4))) = vreg[d0][j];
      }
    }
    #pragma unroll
    for (int s = 0; s < 2; ++s) {
      f16x8 vf[2], pf[4];
      #pragma unroll
      for (int n = 0; n < 2; ++n)
        vf[n] = *(const f16x8*)((const char*)vl + (16 * n + c) * 128 + ((64 * s + 16 * g) ^ swz));
      #pragma unroll
      for (int jq = 0; jq < 4; ++jq)
        pf[jq] = *(const f16x8*)((const char*)pl + (16 * jq + c) * 128 + ((64 * s + 16 * g) ^ swz));
      __builtin_amdgcn_s_setprio(1);
      #pragma unroll
      for (int jq = 0; jq < 4; ++jq)
        #pragma unroll
        for (int n = 0; n < 2; ++n)
          o[jq][2 * h + n] = mfma_16x16x32(pf[jq], vf[n], o[jq][2 * h + n]);
      __builtin_amdgcn_s_setprio(0);
    }
  }

  // ---- stage O into plds [64q][64d] f16 (overwrites P; per-wave DS in-order) ----
  #pragma unroll
  for (int jq = 0; jq < 4; ++jq) {
    #pragma unroll
    for (int r = 0; r < 4; ++r) {
      const int q = 16 * jq + 4 * g + r;
      const int xq = (q & 7) << 4;
      #pragma unroll
      for (int n = 0; n < 4; ++n)
        *(f16*)((char*)pl + ((q * 128 + (16 * n + c) * 2) ^ xq)) = (f16)o[jq][n][r];
    }
  }
  // ---- coalesced readout: lane = q row; 128 B contiguous per row ----
  if (lane < 49) {
    f16* ob = og + ((size_t)bwi * 49 + lane) * 512 + head * 64;
    const int xr = (lane & 7) << 4;
    #pragma unroll
    for (int k = 0; k < 8; ++k) {
      f16x8 v = *(const f16x8*)((const char*)pl + ((lane * 128 + k * 16) ^ xr));
      *(f16x8*)(ob + k * 8) = v;
    }
  }
}

extern "C" void kernel_launch(void* const* d_in, const int* in_sizes, int n_in,
                              void* d_out, int out_size, void* d_ws, size_t ws_size,
                              hipStream_t stream)
{
  const float* x     = (const float*)d_in[0];
  const float* wqkv  = (const float*)d_in[1];
  const float* wproj = (const float*)d_in[2];
  const float* bproj = (const float*)d_in[3];
  float* out = (float*)d_out;

  // workspace layout (bytes); xh and ah share a region (xh dead before attn)
  char* ws = (char*)d_ws;
  f16* zp = (f16*)ws;                               // 1,024 B
  f16* xh = (f16*)(ws + 1024);                      // 104,603,648 B (region 116,006,912)
  f16* ah = xh;                                     // 116,006,912 B (after gemm1)
  f16* qh = (f16*)(ws + 1024 + 116006912LL);        // 116,006,912 B
  f16* kh = qh + 58003456LL;                        // 116,006,912 B
  f16* vh = kh + 58003456LL;                        // 116,011,008 B (+4 KB overrun pad)
  f16* wqkvT  = vh + 58005504LL;                    //   1,572,864 B
  f16* wprojT = wqkvT + 786432LL;                   //     524,288 B  (~466 MB total)

  cvt_x_kernel<<<2048, 256, 0, stream>>>(x, xh, zp);
  cvt_wT_kernel<<<(1536 * 512 + 255) / 256, 256, 0, stream>>>(wqkv, wqkvT, 512, 1536);
  cvt_wT_kernel<<<(512 * 512 + 255) / 256, 256, 0, stream>>>(wproj, wprojT, 512, 512);

  // 886 M-tiles of 128 x 12 N-tiles of 128
  gemm_kernel<0><<<886 * 12, 256, 0, stream>>>(xh, wqkvT, qh, kh, vh, nullptr, nullptr, zp);

  attn_kernel<<<NHW / 4, 256, 0, stream>>>(qh, kh, vh, ah);

  // 799 M-tiles of 128 x 4 N-tiles of 128
  gemm_kernel<1><<<799 * 4, 256, 0, stream>>>(ah, wprojT, nullptr, nullptr, nullptr, out, bproj, zp);
}

// Round 15
// 548.204 us; speedup vs baseline: 1.0524x; 1.0524x over previous
//
#include <hip/hip_runtime.h>
#include <hip/hip_fp16.h>
#include <stdint.h>

typedef _Float16 f16;
typedef __attribute__((ext_vector_type(4))) _Float16 f16x4;
typedef __attribute__((ext_vector_type(8))) _Float16 f16x8;
typedef __attribute__((ext_vector_type(4))) float f32x4;

#define DEVI static __device__ __forceinline__

// ---- constants for this problem ----
#define C_DIM 512
#define M1    113288   // 8*289*49 window-token rows
#define M2    102152   // 8*12769 pixel rows
#define NWIN  289
#define NTOK  49
#define NHW   18496    // 8*289*8 head-windows
#define QKV_STRIDE 3136  // 49*64 per head-window, q/k/v all

DEVI void load_lds16(const f16* g, f16* l) {
  __builtin_amdgcn_global_load_lds((const __attribute__((address_space(1))) void*)g,
                                   (__attribute__((address_space(3))) void*)l,
                                   16, 0, 0);
}

DEVI f32x4 mfma_16x16x32(f16x8 a, f16x8 b, f32x4 c) {
  return __builtin_amdgcn_mfma_f32_16x16x32_f16(a, b, c, 0, 0, 0);
}

// ---------------- x -> f16 (and zero page init) ----------------
__global__ void cvt_x_kernel(const float* __restrict__ x, f16* __restrict__ xh,
                             f16* __restrict__ zp) {
  if (blockIdx.x == 0 && threadIdx.x < 64) {
    ((int4*)zp)[threadIdx.x] = make_int4(0, 0, 0, 0);  // 1024 B zeros
  }
  const int n8 = 6537728;  // 52,301,824 / 8
  int i = blockIdx.x * blockDim.x + threadIdx.x;
  for (; i < n8; i += gridDim.x * blockDim.x) {
    const float4* p = (const float4*)(x) + (size_t)i * 2;
    const float4 a = p[0], b = p[1];
    f16x8 o;
    o[0] = (f16)a.x; o[1] = (f16)a.y; o[2] = (f16)a.z; o[3] = (f16)a.w;
    o[4] = (f16)b.x; o[5] = (f16)b.y; o[6] = (f16)b.z; o[7] = (f16)b.w;
    *(f16x8*)(xh + (size_t)i * 8) = o;
  }
}

// ---------------- W [K][N] -> Wt f16 [N][K] ----------------
__global__ void cvt_wT_kernel(const float* __restrict__ w, f16* __restrict__ wt,
                              int K, int N) {
  const int i = blockIdx.x * blockDim.x + threadIdx.x;
  if (i < K * N) {
    const int n = i / K;
    const int k = i - n * K;
    wt[i] = (f16)w[(size_t)k * N + n];
  }
}

// ================= GEMM: C[M][N] = gather(A)[M][512] @ Bt[N][512]^T =============
// 128x128 block tile, 4 waves (64x64 per wave), BK=64, SINGLE 32 KB LDS buffer,
// 2 barriers per K-tile. LDS [128 rows][8 chunks of 16B], phys chunk =
// logical ^ (row&7) via inverse-swizzled GLOBAL source + linear gload dest.
// MODE 0 epilogue: LDS-transpose (reuse As/Bs space) -> coalesced f16x8 stores.
// MODE 0: q/k/v all -> [hw][49][64] f16 (stride 3136)
// MODE 1: A = ah (window-merge gather); out -> fp32 + bias (scatter epilogue)
template<int MODE>
__global__ __launch_bounds__(256, 2)
void gemm_kernel(const f16* __restrict__ A, const f16* __restrict__ Bt,
                 f16* __restrict__ qo, f16* __restrict__ ko, f16* __restrict__ vo,
                 float* __restrict__ out, const float* __restrict__ bias,
                 const f16* __restrict__ zp)
{
  __shared__ __align__(16) f16 S[16384];  // 32 KB: As | Bs during K-loop; Cs in epilogue
  f16* As = S;
  f16* Bs = S + 8192;

  const int tid  = threadIdx.x;
  const int wave = tid >> 6;
  const int lane = tid & 63;
  const int l16  = lane & 15;
  const int g    = lane >> 4;

  constexpr int NTN = (MODE == 0) ? 12 : 4;
  // bijective XCD swizzle, tn-fastest (all N-passes of an A-tile on one XCD)
  const int nwg = gridDim.x;
  const int qq = nwg >> 3, rr = nwg & 7;
  const int xcd = blockIdx.x & 7, ib = blockIdx.x >> 3;
  const int wg = (xcd < rr ? xcd * (qq + 1) : rr * (qq + 1) + (xcd - rr) * qq) + ib;
  const int tn = wg % NTN;
  const int tm = wg / NTN;

  // ---- staging source pointers: 4 row-groups of 32, one 16B chunk per thread ----
  const int srow  = tid >> 3;   // 0..31
  const int chunk = tid & 7;    // phys chunk slot (linear LDS dest)
  const int lc    = chunk ^ (srow & 7);  // logical k-chunk fetched into this slot
  const f16* asrc[4];
  const f16* bsrc[4];
  #pragma unroll
  for (int c = 0; c < 4; ++c) {
    const int m = tm * 128 + c * 32 + srow;
    long src = 0; bool valid;
    if (MODE == 0) {
      const int b   = m / 14161;               // 289*49
      const int rem = m - b * 14161;
      const int wi  = rem / 49;
      const int t   = rem - wi * 49;
      const int wh = wi / 17, ww = wi - (wi / 17) * 17;
      const int th = t / 7,   tw = t - (t / 7) * 7;
      const int h = wh * 7 + th, w = ww * 7 + tw;
      valid = (m < M1) && (h < 113) && (w < 113);
      src = (long)b * 12769 + h * 113 + w;
    } else {
      const int b = m / 12769;
      const int p = m - b * 12769;
      const int h = p / 113, w = p - (p / 113) * 113;
      valid = (m < M2);
      src = (long)((b * NWIN + (h / 7) * 17 + (w / 7)) * NTOK + (h % 7) * 7 + (w % 7));
    }
    asrc[c] = valid ? (A + src * C_DIM + lc * 8) : zp;
    bsrc[c] = Bt + (long)(tn * 128 + c * 32 + srow) * C_DIM + lc * 8;
  }

  // ---- ds_read byte offsets (kh=0; kh=1 => ^64) ----
  int aoff[4], boff[4];
  #pragma unroll
  for (int i = 0; i < 4; ++i) {
    const int ra = (wave >> 1) * 64 + 16 * i + l16;
    aoff[i] = ra * 128 + ((g ^ (l16 & 7)) << 4);
    const int rb = (wave & 1) * 64 + 16 * i + l16;
    boff[i] = rb * 128 + ((g ^ (l16 & 7)) << 4);
  }

  f32x4 acc[4][4];
  #pragma unroll
  for (int i = 0; i < 4; ++i)
    #pragma unroll
    for (int j = 0; j < 4; ++j)
      acc[i][j] = (f32x4){0.f, 0.f, 0.f, 0.f};

  for (int kk = 0; kk < 8; ++kk) {       // K = 512 = 8 * 64
    __syncthreads();                     // prior tile's reads done (WAR)
    #pragma unroll
    for (int c = 0; c < 4; ++c) {
      load_lds16(asrc[c], &As[c * 2048 + wave * 512]);
      asrc[c] += 64;
    }
    #pragma unroll
    for (int c = 0; c < 4; ++c) {
      load_lds16(bsrc[c], &Bs[c * 2048 + wave * 512]);
      bsrc[c] += 64;
    }
    __syncthreads();                     // staging complete (vmcnt drained)

    #pragma unroll
    for (int kh = 0; kh < 2; ++kh) {
      f16x8 af[4], bf[4];
      #pragma unroll
      for (int i = 0; i < 4; ++i) af[i] = *(const f16x8*)((const char*)As + (aoff[i] ^ (kh << 6)));
      #pragma unroll
      for (int j = 0; j < 4; ++j) bf[j] = *(const f16x8*)((const char*)Bs + (boff[j] ^ (kh << 6)));
      #pragma unroll
      for (int i = 0; i < 4; ++i)
        #pragma unroll
        for (int j = 0; j < 4; ++j)
          acc[i][j] = mfma_16x16x32(af[i], bf[j], acc[i][j]);
    }
  }

  // ---- epilogue ----
  if (MODE == 0) {
    // LDS-transpose: Cs[128 rows][128 cols] f16, byte-swizzle ^((row>>2&3)<<5)
    __syncthreads();                       // all waves done reading As/Bs
    char* Cs = (char*)S;
    const int rw0 = (wave >> 1) * 64 + g * 4;
    const int cl0 = (wave & 1) * 64 + l16;
    #pragma unroll
    for (int i = 0; i < 4; ++i) {
      #pragma unroll
      for (int rg = 0; rg < 4; ++rg) {
        const int row = rw0 + i * 16 + rg;
        const int xr  = ((row >> 2) & 3) << 5;
        #pragma unroll
        for (int j = 0; j < 4; ++j) {
          const int col = cl0 + j * 16;
          *(f16*)(Cs + row * 256 + ((col * 2) ^ xr)) = (f16)acc[i][j][rg];
        }
      }
    }
    __syncthreads();
    // read-out: thread -> (row, 64-col half); coalesced 16B global stores
    const int row  = tid >> 1;
    const int half = tid & 1;
    const int m = tm * 128 + row;
    if (m < M1) {
      const int bwi = m / 49;
      const int t   = m - bwi * 49;
      const int cwi = tn * 2 + half;            // 64-col strip index 0..23
      f16* outw = (cwi < 8) ? qo : (cwi < 16) ? ko : vo;
      const int head = cwi & 7;
      f16* dst = outw + (size_t)(bwi * 8 + head) * QKV_STRIDE + t * 64;
      const int xr = ((row >> 2) & 3) << 5;
      #pragma unroll
      for (int c = 0; c < 8; ++c) {
        f16x8 v = *(const f16x8*)(Cs + row * 256 + ((half * 128 + c * 16) ^ xr));
        *(f16x8*)(dst + c * 8) = v;
      }
    }
  } else {
    const int rowb = tm * 128 + (wave >> 1) * 64 + g * 4;
    const int colb = tn * 128 + (wave & 1) * 64 + l16;
    #pragma unroll
    for (int i = 0; i < 4; ++i) {
      #pragma unroll
      for (int j = 0; j < 4; ++j) {
        const int col = colb + j * 16;
        const float bb = bias[col];
        #pragma unroll
        for (int rg = 0; rg < 4; ++rg) {
          const int m = rowb + i * 16 + rg;
          if (m < M2) out[(size_t)m * C_DIM + col] = acc[i][j][rg] + bb;
        }
      }
    }
  }
}

// ---------------- MFMA attention: one wave per (b, window, head) ----------------
// r8 split-buffer version + T5 setprio around the MFMA clusters (attn is the
// m191-applicable regime: independent waves, no inter-wave barriers).
__global__ __launch_bounds__(256)
void attn_kernel(const f16* __restrict__ qg, const f16* __restrict__ kg,
                 const f16* __restrict__ vg, f16* __restrict__ og)
{
  __shared__ __align__(16) f16 plds[4][4096];  // per-wave [64q][64key], XOR-swizzled
  __shared__ __align__(16) f16 vlds[4][2048];  // per-wave [32d][64t] half, XOR-swizzled
  const int tid  = threadIdx.x;
  const int wv   = tid >> 6;
  const int lane = tid & 63;
  const int g    = lane >> 4;
  const int c    = lane & 15;
  const int hw   = blockIdx.x * 4 + wv;
  const int bwi  = hw >> 3;
  const int head = hw & 7;
  const int wi   = bwi % NWIN;
  const size_t bqk = (size_t)hw * QKV_STRIDE;
  const f16* vp = vg + (size_t)hw * QKV_STRIDE;

  // ---- V tile -> registers early (latency hides under QK^T); zero pad rows ----
  f16x8 vreg[8];
  #pragma unroll
  for (int d0 = 0; d0 < 8; ++d0)
    vreg[d0] = *(const f16x8*)(vp + lane * 64 + d0 * 8);
  if (lane >= 49) {
    #pragma unroll
    for (int d0 = 0; d0 < 8; ++d0) vreg[d0] = (f16x8){};
  }

  // pad-bit mask for tokens 0..48 of this window
  const int wh = wi / 17, ww = wi - (wi / 17) * 17;
  unsigned long long pm = 0;
  if (wh == 16) pm |= (((1ull << 49) - 1) & ~0x7Full);           // rows th>=1
  if (ww == 16) {
    unsigned long long cm = 0;
    #pragma unroll
    for (int r7 = 0; r7 < 7; ++r7) cm |= 0x7Eull << (7 * r7);    // cols tw>=1
    pm |= cm;
  }

  // ---- S^T = K * Q^T ----
  f32x4 acc[4][4];
  #pragma unroll
  for (int i = 0; i < 4; ++i)
    #pragma unroll
    for (int j = 0; j < 4; ++j) acc[i][j] = (f32x4){0.f, 0.f, 0.f, 0.f};

  const f16* kp = kg + bqk;
  const f16* qp = qg + bqk;
  __builtin_amdgcn_s_setprio(1);
  #pragma unroll
  for (int s = 0; s < 2; ++s) {
    f16x8 kf[4], qf[4];
    #pragma unroll
    for (int i = 0; i < 4; ++i) kf[i] = *(const f16x8*)(kp + (16 * i + c) * 64 + 32 * s + 8 * g);
    #pragma unroll
    for (int j = 0; j < 4; ++j) qf[j] = *(const f16x8*)(qp + (16 * j + c) * 64 + 32 * s + 8 * g);
    #pragma unroll
    for (int i = 0; i < 4; ++i)
      #pragma unroll
      for (int j = 0; j < 4; ++j)
        acc[i][j] = mfma_16x16x32(kf[i], qf[j], acc[i][j]);
  }
  __builtin_amdgcn_s_setprio(0);

  // ---- mask + exp + per-query denom (q = 16j + c; key = 16i + 4g + r) ----
  float invs[4];
  #pragma unroll
  for (int j = 0; j < 4; ++j) {
    const int q = 16 * j + c;
    const int padq = (int)((pm >> q) & 1);
    float sj = 0.f;
    #pragma unroll
    for (int i = 0; i < 4; ++i) {
      #pragma unroll
      for (int r = 0; r < 4; ++r) {
        const int key = 16 * i + 4 * g + r;
        const int padk = (int)((pm >> key) & 1);
        float sv = acc[i][j][r] * 0.125f + ((padk ^ padq) ? -1000.f : 0.f);
        float p = __expf(sv);
        if (i == 3) p = ((4 * g + r) == 0) ? p : 0.f;   // keys >= 49 forced 0
        acc[i][j][r] = p;
        sj += p;
      }
    }
    invs[j] = sj;
  }
  #pragma unroll
  for (int j = 0; j < 4; ++j) {
    float sj = invs[j];
    sj += __shfl_xor(sj, 16);
    sj += __shfl_xor(sj, 32);
    invs[j] = 1.0f / sj;
  }

  // ---- pack normalized P to f16, write LDS [q][key] (byte ^= (q&7)<<4) ----
  f16* pl = &plds[wv][0];
  const int swz = (c & 7) << 4;   // c&7 == q&7 for all j
  #pragma unroll
  for (int j = 0; j < 4; ++j) {
    const int q = 16 * j + c;
    const float inv = invs[j];
    #pragma unroll
    for (int i = 0; i < 4; ++i) {
      f16x4 pk;
      pk[0] = (f16)(acc[i][j][0] * inv);
      pk[1] = (f16)(acc[i][j][1] * inv);
      pk[2] = (f16)(acc[i][j][2] * inv);
      pk[3] = (f16)(acc[i][j][3] * inv);
      *(f16x4*)((char*)pl + q * 128 + ((32 * i + 8 * g) ^ swz)) = pk;
    }
  }

  // ---- O = P * V in two d-halves; V^T built in LDS from vreg ----
  f16* vl = &vlds[wv][0];
  f32x4 o[4][4];
  #pragma unroll
  for (int i = 0; i < 4; ++i)
    #pragma unroll
    for (int j = 0; j < 4; ++j) o[i][j] = (f32x4){0.f, 0.f, 0.f, 0.f};

  #pragma unroll
  for (int h = 0; h < 2; ++h) {
    #pragma unroll
    for (int q4 = 0; q4 < 4; ++q4) {
      const int d0 = 4 * h + q4;
      #pragma unroll
      for (int j = 0; j < 8; ++j) {
        const int dr = (8 * d0 + j) & 31;
        *(f16*)((char*)vl + dr * 128 + ((lane * 2) ^ (j << 4))) = vreg[d0][j];
      }
    }
    #pragma unroll
    for (int s = 0; s < 2; ++s) {
      f16x8 vf[2], pf[4];
      #pragma unroll
      for (int n = 0; n < 2; ++n)
        vf[n] = *(const f16x8*)((const char*)vl + (16 * n + c) * 128 + ((64 * s + 16 * g) ^ swz));
      #pragma unroll
      for (int jq = 0; jq < 4; ++jq)
        pf[jq] = *(const f16x8*)((const char*)pl + (16 * jq + c) * 128 + ((64 * s + 16 * g) ^ swz));
      __builtin_amdgcn_s_setprio(1);
      #pragma unroll
      for (int jq = 0; jq < 4; ++jq)
        #pragma unroll
        for (int n = 0; n < 2; ++n)
          o[jq][2 * h + n] = mfma_16x16x32(pf[jq], vf[n], o[jq][2 * h + n]);
      __builtin_amdgcn_s_setprio(0);
    }
  }

  // ---- store O rows q = 16jq + 4g + r (q<49), cols d = 16n + c ----
  f16* ob = og + ((size_t)bwi * 49) * 512 + head * 64;
  #pragma unroll
  for (int jq = 0; jq < 4; ++jq) {
    #pragma unroll
    for (int r = 0; r < 4; ++r) {
      const int q = 16 * jq + 4 * g + r;
      if (q < 49) {
        #pragma unroll
        for (int n = 0; n < 4; ++n)
          ob[(size_t)q * 512 + 16 * n + c] = (f16)o[jq][n][r];
      }
    }
  }
}

extern "C" void kernel_launch(void* const* d_in, const int* in_sizes, int n_in,
                              void* d_out, int out_size, void* d_ws, size_t ws_size,
                              hipStream_t stream)
{
  const float* x     = (const float*)d_in[0];
  const float* wqkv  = (const float*)d_in[1];
  const float* wproj = (const float*)d_in[2];
  const float* bproj = (const float*)d_in[3];
  float* out = (float*)d_out;

  // workspace layout (bytes); xh and ah share a region (xh dead before attn)
  char* ws = (char*)d_ws;
  f16* zp = (f16*)ws;                               // 1,024 B
  f16* xh = (f16*)(ws + 1024);                      // 104,603,648 B (region 116,006,912)
  f16* ah = xh;                                     // 116,006,912 B (after gemm1)
  f16* qh = (f16*)(ws + 1024 + 116006912LL);        // 116,006,912 B
  f16* kh = qh + 58003456LL;                        // 116,006,912 B
  f16* vh = kh + 58003456LL;                        // 116,011,008 B (+4 KB overrun pad)
  f16* wqkvT  = vh + 58005504LL;                    //   1,572,864 B
  f16* wprojT = wqkvT + 786432LL;                   //     524,288 B  (~466 MB total)

  cvt_x_kernel<<<2048, 256, 0, stream>>>(x, xh, zp);
  cvt_wT_kernel<<<(1536 * 512 + 255) / 256, 256, 0, stream>>>(wqkv, wqkvT, 512, 1536);
  cvt_wT_kernel<<<(512 * 512 + 255) / 256, 256, 0, stream>>>(wproj, wprojT, 512, 512);

  // 886 M-tiles of 128 x 12 N-tiles of 128
  gemm_kernel<0><<<886 * 12, 256, 0, stream>>>(xh, wqkvT, qh, kh, vh, nullptr, nullptr, zp);

  attn_kernel<<<NHW / 4, 256, 0, stream>>>(qh, kh, vh, ah);

  // 799 M-tiles of 128 x 4 N-tiles of 128
  gemm_kernel<1><<<799 * 4, 256, 0, stream>>>(ah, wprojT, nullptr, nullptr, nullptr, out, bproj, zp);
}